// Round 3
// baseline (4738.980 us; speedup 1.0000x reference)
//
#include <hip/hip_runtime.h>
#include <stdint.h>

// ---------------------------------------------------------------------------
// BasicLSTM on MI355X: persistent pipelined 2-layer LSTM.
//
// Grid: 256 WGs x 256 threads, REGULAR launch (cooperative launch is not
// graph-capturable). Co-residency by construction: __launch_bounds__(256,1)
// -> 1 block/CU, grid=256 = CU count, so all 32 WGs of a barrier group are
// always resident.
//
//   blockIdx: g = blk & 7 (batch group, 16 rows), sub = blk >> 3,
//             layer = sub >> 4, rt = sub & 15 (hidden slice of 32).
// Each WG owns gate rows {gate*512 + rt*32 .. +31, gate=0..3} for its layer
// (N=128 cols), batch tile M=16, K = 768 (L0: 256 x + 512 h) or 1024 (L1).
// Weights live in registers as MFMA B-fragments for all 513 steps.
// Per step: stage A (x/h) -> LDS, 16x16x32 bf16 MFMA K-loop, fp32 gates,
// c-state in registers, h -> global (bf16, agent-scope stores),
// then a 32-WG monotonic-counter barrier (groups are independent).
//
// ROUND-2 BUG FIX: h staging chunks were 8 B (4 bf16) but the task
// decomposition assumes 16 B (8 bf16) — half of each h vector was never
// loaded and the upper K range of the A tile was UNINITIALIZED LDS
// (eager absmax 454 vs replay 0.75 nondeterminism signature). Now each
// chunk does two 8B agent-scope loads + one 16B LDS store.
// ---------------------------------------------------------------------------

using s16x8 = __attribute__((ext_vector_type(8))) short;   // 8 bf16 = 4 VGPRs
using f32x4 = __attribute__((ext_vector_type(4))) float;
typedef unsigned long long ull;

#define WSB0_OFF 0          // ushort elems; L0 frags: 16*8*24*512 = 1572864
#define WSB1_OFF 1572864    // L1 frags: 16*8*32*512 = 2097152
#define HB0_OFF  3670016    // h0 double buffer: 2*128*512 = 131072
#define HB1_OFF  3801088    // h1 double buffer: 131072  (end 3932160 elems)
#define BARS_BYTE_OFF 7864320  // 128 uints (8 groups x 16 spacing)

__device__ __forceinline__ float bf2f(unsigned short u) {
    unsigned v = ((unsigned)u) << 16;
    return __builtin_bit_cast(float, v);
}
__device__ __forceinline__ unsigned short f2bf(float f) {
    unsigned x = __builtin_bit_cast(unsigned, f);
    x += 0x7FFFu + ((x >> 16) & 1u);          // RNE (finite values only)
    return (unsigned short)(x >> 16);
}
__device__ __forceinline__ float sigm(float x) { return 1.f / (1.f + __expf(-x)); }
__device__ __forceinline__ float tanhc(float x) {
    x = fminf(15.f, fmaxf(-15.f, x));
    float e = __expf(-2.f * x);
    return (1.f - e) / (1.f + e);
}

// ---------------------------------------------------------------------------
// Prep: reformat weights (fp32 -> bf16 MFMA B-fragments), zero h parity-1
// buffers and barrier counters. Re-run every call (ws is re-poisoned).
// ---------------------------------------------------------------------------
__device__ __forceinline__ void store_frag(unsigned short* dst, int n, int kc, int KT,
                                           const float* src) {
    s16x8 v;
#pragma unroll
    for (int e = 0; e < 8; ++e) v[e] = (short)f2bf(src[e]);
    int gate = n >> 9, hid = n & 511;
    int rt = hid >> 5, jh = hid & 31;
    int colL = gate * 32 + jh;
    int nt = colL >> 4, lo = colL & 15;
    int kt = kc >> 2, q = kc & 3;
    int lane = q * 16 + lo;
    size_t off = ((((size_t)rt * 8 + nt) * KT + kt) * 64 + lane) * 8;
    *(s16x8*)(dst + off) = v;
}

__global__ void k_prep(const float* __restrict__ wih0, const float* __restrict__ whh0,
                       const float* __restrict__ wih1, const float* __restrict__ whh1,
                       unsigned short* __restrict__ wsB0, unsigned short* __restrict__ wsB1,
                       unsigned short* __restrict__ hb0, unsigned short* __restrict__ hb1,
                       unsigned* __restrict__ bars) {
    int idx = blockIdx.x * 256 + threadIdx.x;
    if (idx < 196608) {                       // L0: 2048 rows x 96 k-chunks
        int n = idx / 96, kc = idx - n * 96;
        int k = kc * 8;
        const float* src = (k < 256) ? (wih0 + (size_t)n * 256 + k)
                                     : (whh0 + (size_t)n * 512 + (k - 256));
        store_frag(wsB0, n, kc, 24, src);
    } else if (idx < 458752) {                // L1: 2048 rows x 128 k-chunks
        int j = idx - 196608;
        int n = j >> 7, kc = j & 127;
        int k = kc * 8;
        const float* src = (k < 512) ? (wih1 + (size_t)n * 512 + k)
                                     : (whh1 + (size_t)n * 512 + (k - 512));
        store_frag(wsB1, n, kc, 32, src);
    } else {
        int z = idx - 458752;
        if (z < 8192) {                       // zero hb0 parity 1
            ull* p = (ull*)(hb0 + 65536 + (size_t)z * 8);
            p[0] = 0ull; p[1] = 0ull;
        } else if (z < 16384) {               // zero hb1 parity 1
            ull* p = (ull*)(hb1 + 65536 + (size_t)(z - 8192) * 8);
            p[0] = 0ull; p[1] = 0ull;
        } else if (z < 16512) {
            bars[z - 16384] = 0u;
        }
    }
}

// ---------------------------------------------------------------------------
// Persistent LSTM kernel
// ---------------------------------------------------------------------------
template <int LAYER, int KT>
__device__ __forceinline__ void run_layer(const float* __restrict__ x,
                                          const unsigned short* __restrict__ wsB,
                                          unsigned short* hsrc0,   // L0: hb0(self h) ; L1: hb0(y0)
                                          unsigned short* hself,   // write target (hb0 / hb1)
                                          unsigned* bar,
                                          float bv0, float bv1,
                                          int g, int rt, int w, int lane, int tid,
                                          char* At, float* gb, unsigned short* hx) {
    constexpr int PITCH = KT * 64 + 16;  // bytes per A row (+16B pad: 2-way bank alias, free)
    const int lm = lane & 15, lq = lane >> 4;

    // --- weight fragments into registers (live across all 513 steps) ---
    s16x8 bfr0[KT], bfr1[KT];
    {
        const unsigned short* base = wsB + (((size_t)rt * 8 + 2 * w) * KT) * 512;
#pragma unroll
        for (int kt = 0; kt < KT; ++kt) {
            bfr0[kt] = *(const s16x8*)(base + ((size_t)kt * 64 + lane) * 8);
            bfr1[kt] = *(const s16x8*)(base + (((size_t)KT + kt) * 64 + lane) * 8);
        }
    }

    float c0 = 0.f, c1 = 0.f;                 // cell state: (tb,jh) and (tb+8,jh)
    const int tb = tid >> 5, tjh = tid & 31;

#pragma unroll 1
    for (int s = 0; s <= 512; ++s) {
        const bool active = LAYER ? (s >= 1) : (s < 512);
        if (active) {
            const int tt = LAYER ? (s - 1) : s;
            // ---- stage A tile into LDS ----
            if (LAYER == 0) {
                const int pr = (s + 1) & 1;   // == (s-1)&1
#pragma unroll
                for (int i = 0; i < 6; ++i) {
                    int task = tid + i * 256;          // 16 rows x 96 tasks
                    int row = task / 96, tau = task - row * 96;
                    char* dst = At + row * PITCH;
                    if (tau < 32) {                    // x part: 8 fp32 -> 8 bf16
                        const float* src = x + ((size_t)(g * 16 + row) * 512 + tt) * 256 + tau * 8;
                        f32x4 fa = *(const f32x4*)(src);
                        f32x4 fb = *(const f32x4*)(src + 4);
                        s16x8 v;
#pragma unroll
                        for (int e = 0; e < 4; ++e) { v[e] = (short)f2bf(fa[e]); v[4 + e] = (short)f2bf(fb[e]); }
                        *(s16x8*)(dst + tau * 16) = v;
                    } else {                           // h part: 8 bf16 via 2x8B coherent loads
                        int c8 = tau - 32;             // 0..63, 8 elems each
                        const ull* sp = (const ull*)(hsrc0 +
                            (size_t)(pr * 128 + g * 16 + row) * 512 + c8 * 8);
                        ull v0 = __hip_atomic_load(sp,     __ATOMIC_RELAXED, __HIP_MEMORY_SCOPE_AGENT);
                        ull v1 = __hip_atomic_load(sp + 1, __ATOMIC_RELAXED, __HIP_MEMORY_SCOPE_AGENT);
                        ull* d = (ull*)(dst + 512 + c8 * 16);
                        d[0] = v0; d[1] = v1;
                    }
                }
            } else {
                const int pr0 = (s + 1) & 1, pr1 = s & 1;
#pragma unroll
                for (int i = 0; i < 8; ++i) {
                    int task = tid + i * 256;          // 16 rows x 128 chunks (8 elems each)
                    int row = task >> 7, c8 = task & 127;
                    const unsigned short* sp = (c8 < 64)
                        ? (hsrc0 + (size_t)(pr0 * 128 + g * 16 + row) * 512 + c8 * 8)
                        : (hself + (size_t)(pr1 * 128 + g * 16 + row) * 512 + (c8 - 64) * 8);
                    ull v0 = __hip_atomic_load((const ull*)sp,     __ATOMIC_RELAXED, __HIP_MEMORY_SCOPE_AGENT);
                    ull v1 = __hip_atomic_load((const ull*)sp + 1, __ATOMIC_RELAXED, __HIP_MEMORY_SCOPE_AGENT);
                    ull* d = (ull*)(At + row * PITCH + c8 * 16);
                    d[0] = v0; d[1] = v1;
                }
            }
            __syncthreads();

            // ---- MFMA K-loop: D[16 x 32cols] for gate w ----
            f32x4 acc0 = {0.f, 0.f, 0.f, 0.f}, acc1 = {0.f, 0.f, 0.f, 0.f};
            const char* ap = At + lm * PITCH + lq * 16;
#pragma unroll
            for (int kt = 0; kt < KT; ++kt) {
                s16x8 a = *(const s16x8*)(ap + kt * 64);
                acc0 = __builtin_amdgcn_mfma_f32_16x16x32_bf16(a, bfr0[kt], acc0, 0, 0, 0);
                acc1 = __builtin_amdgcn_mfma_f32_16x16x32_bf16(a, bfr1[kt], acc1, 0, 0, 0);
            }

            // ---- gates to LDS (gbuf[gate][m][jh], pitch 33) ----
#pragma unroll
            for (int r = 0; r < 4; ++r) {
                gb[(w * 16 + 4 * lq + r) * 33 + lm]      = acc0[r] + bv0;
                gb[(w * 16 + 4 * lq + r) * 33 + 16 + lm] = acc1[r] + bv1;
            }
            __syncthreads();

            // ---- nonlinearity + state update (2 (b,jh) pairs per thread) ----
            {
                float gi = gb[(0 * 16 + tb) * 33 + tjh];
                float gf = gb[(1 * 16 + tb) * 33 + tjh];
                float gg = gb[(2 * 16 + tb) * 33 + tjh];
                float go = gb[(3 * 16 + tb) * 33 + tjh];
                c0 = sigm(gf) * c0 + sigm(gi) * tanhc(gg);
                hx[tb * 32 + tjh] = f2bf(sigm(go) * tanhc(c0));

                float hi = gb[(0 * 16 + tb + 8) * 33 + tjh];
                float hf = gb[(1 * 16 + tb + 8) * 33 + tjh];
                float hg = gb[(2 * 16 + tb + 8) * 33 + tjh];
                float ho = gb[(3 * 16 + tb + 8) * 33 + tjh];
                c1 = sigm(hf) * c1 + sigm(hi) * tanhc(hg);
                hx[(tb + 8) * 32 + tjh] = f2bf(sigm(ho) * tanhc(c1));
            }
            __syncthreads();

            // ---- packed coherent h store (8B agent-scope) ----
            if (tid < 128) {
                const int pw = LAYER ? ((s + 1) & 1) : (s & 1);
                int row = tid >> 3, cc = tid & 7;
                ull v = *(const ull*)(hx + row * 32 + cc * 4);
                __hip_atomic_store(
                    (ull*)(hself + (size_t)(pw * 128 + g * 16 + row) * 512 + rt * 32 + cc * 4),
                    v, __ATOMIC_RELAXED, __HIP_MEMORY_SCOPE_AGENT);
            }
        }

        // ---- 32-WG group barrier (monotonic counter, release/acquire) ----
        __syncthreads();
        if (tid == 0) {
            __hip_atomic_fetch_add(bar, 1u, __ATOMIC_RELEASE, __HIP_MEMORY_SCOPE_AGENT);
            unsigned tgt = 32u * (unsigned)(s + 1);
            while (__hip_atomic_load(bar, __ATOMIC_ACQUIRE, __HIP_MEMORY_SCOPE_AGENT) < tgt)
                __builtin_amdgcn_s_sleep(1);
        }
        __syncthreads();
    }
}

__launch_bounds__(256, 1)
__global__ void k_lstm(const float* __restrict__ x,
                       const float* __restrict__ b0,
                       const float* __restrict__ b1,
                       const unsigned short* __restrict__ wsB0,
                       const unsigned short* __restrict__ wsB1,
                       unsigned short* hb0, unsigned short* hb1,
                       unsigned* bars) {
    __shared__ __align__(16) char Atile[16 * 2064];      // A tile, max pitch (L1)
    __shared__ float gbuf[4][16][33];                    // gate redistribution
    __shared__ unsigned short hexch[16][32];             // h packing

    const int tid = threadIdx.x;
    const int g = blockIdx.x & 7, sub = blockIdx.x >> 3;
    const int layer = sub >> 4, rt = sub & 15;
    const int w = tid >> 6, lane = tid & 63;
    const int lm = lane & 15;
    unsigned* bar = bars + g * 16;
    const float* bias = layer ? b1 : b0;
    const float bv0 = bias[w * 512 + rt * 32 + lm];
    const float bv1 = bias[w * 512 + rt * 32 + 16 + lm];

    if (layer == 0)
        run_layer<0, 24>(x, wsB0, hb0, hb0, bar, bv0, bv1, g, rt, w, lane, tid,
                         Atile, &gbuf[0][0][0], &hexch[0][0]);
    else
        run_layer<1, 32>(x, wsB1, hb0, hb1, bar, bv0, bv1, g, rt, w, lane, tid,
                         Atile, &gbuf[0][0][0], &hexch[0][0]);
}

// ---------------------------------------------------------------------------
// FC epilogue: out[i] = dot(hn[i], fc_w) + fc_b,  hn = [h0_final; h1_final]
// ---------------------------------------------------------------------------
__global__ void k_fc(const unsigned short* __restrict__ hb0,
                     const unsigned short* __restrict__ hb1,
                     const float* __restrict__ fcw, const float* __restrict__ fcb,
                     float* __restrict__ out) {
    int i = blockIdx.x, lane = threadIdx.x;
    const unsigned short* hrow = (i < 128) ? (hb0 + (size_t)(128 + i) * 512)   // parity 1
                                           : (hb1 + (size_t)(128 + (i - 128)) * 512);
    float ssum = 0.f;
    int j0 = lane * 8;
#pragma unroll
    for (int e = 0; e < 8; ++e) ssum += bf2f(hrow[j0 + e]) * fcw[j0 + e];
#pragma unroll
    for (int off2 = 32; off2 > 0; off2 >>= 1) ssum += __shfl_down(ssum, off2);
    if (lane == 0) out[i] = ssum + fcb[0];
}

// ---------------------------------------------------------------------------
extern "C" void kernel_launch(void* const* d_in, const int* in_sizes, int n_in,
                              void* d_out, int out_size, void* d_ws, size_t ws_size,
                              hipStream_t stream) {
    const float* x    = (const float*)d_in[0];
    const float* wih0 = (const float*)d_in[1];
    const float* whh0 = (const float*)d_in[2];
    const float* b0   = (const float*)d_in[3];
    const float* wih1 = (const float*)d_in[4];
    const float* whh1 = (const float*)d_in[5];
    const float* b1   = (const float*)d_in[6];
    const float* fcw  = (const float*)d_in[7];
    const float* fcb  = (const float*)d_in[8];

    unsigned short* wsB0 = (unsigned short*)d_ws;
    unsigned short* wsB1 = wsB0 + WSB1_OFF;
    unsigned short* hb0  = wsB0 + HB0_OFF;
    unsigned short* hb1  = wsB0 + HB1_OFF;
    unsigned* bars = (unsigned*)((char*)d_ws + BARS_BYTE_OFF);
    float* out = (float*)d_out;

    k_prep<<<dim3(1857), dim3(256), 0, stream>>>(wih0, whh0, wih1, whh1,
                                                 wsB0, wsB1, hb0, hb1, bars);

    // Regular launch (graph-capturable). Co-residency by construction:
    // 1 block/CU x 256 CUs; groups of 32 WGs self-synchronize.
    k_lstm<<<dim3(256), dim3(256), 0, stream>>>(x, b0, b1, wsB0, wsB1, hb0, hb1, bars);

    k_fc<<<dim3(256), dim3(64), 0, stream>>>(hb0, hb1, fcw, fcb, out);
}